// Round 8
// baseline (55.686 us; speedup 1.0000x reference)
//
#include <hip/hip_runtime.h>
#include <hip/hip_bf16.h>

// Problem constants
#define BB 8
#define CC 64
#define OO 64
#define HH 128
#define WWI 128
#define HWSZ (HH * WWI)     // 16384
#define KK 9                // 3x3 taps
#define II (KK * CC)        // 576

// patch / window geometry (main kernel)
#define PXW 16              // patch width  (x)
#define PYH 16              // patch height (y)
#define WNX 24              // window cols = PXW + 8
#define WNY 24              // window rows = PYH + 8
#define WROWS (WNX * WNY)   // 576 window rows, each 64 ch * 2B = 128B -> 72KB

typedef __attribute__((ext_vector_type(8))) short bf16x8;
typedef __attribute__((ext_vector_type(4))) float f32x4;
typedef __attribute__((ext_vector_type(2))) float f32x2;
typedef __attribute__((ext_vector_type(4))) unsigned int uint4v;

__device__ __forceinline__ int iclamp(int v, int lo, int hi) {
    return v < lo ? lo : (v > hi ? hi : v);
}
__device__ __forceinline__ unsigned short f2bf(float f) {  // RNE
    unsigned u = __float_as_uint(f);
    return (unsigned short)((u + 0x7fffu + ((u >> 16) & 1u)) >> 16);
}
// bf16 pair -> f32x2 {lo, hi} (hi keeps packed garbage cleared via AND)
__device__ __forceinline__ f32x2 unpk(unsigned u) {
    f32x2 r;
    r.x = __uint_as_float(u << 16);
    r.y = __uint_as_float(u & 0xffff0000u);
    return r;
}

// ---------- prep 1: x [B][C][H][W] f32 -> xt [B][H][W][C] bf16 (LDS transpose)
__global__ __launch_bounds__(256) void prep_xt(const float* __restrict__ x,
                                               unsigned short* __restrict__ xt) {
    __shared__ float tile[64][65];
    const int blk = blockIdx.x;
    const int b = blk & 7;
    const int p0 = (blk >> 3) * 64;
    const int t = threadIdx.x;
    const int a = t >> 6;   // 0..3
    const int q = t & 63;   // 0..63
    const float* xb = x + (size_t)b * CC * HWSZ + p0;
#pragma unroll
    for (int r = 0; r < 16; ++r) {
        int c = r * 4 + a;
        tile[c][q] = xb[(size_t)c * HWSZ + q];   // coalesced read
    }
    __syncthreads();
    unsigned short* xo = xt + ((size_t)b * HWSZ + p0) * CC;
#pragma unroll
    for (int r = 0; r < 16; ++r) {
        int pl = r * 4 + a;
        xo[(size_t)pl * CC + q] = f2bf(tile[q][pl]);  // coalesced 2B x 64 write
    }
}

// ---------- prep 2: W -> fragment-ordered bf16 layout
// waf[slab][lane][j], slab = (k*2+kc)*4 + m, value =
//   W.flat[o = m*16+(lane&15)][i = k*64 + kc*32 + (lane>>4)*8 + j]
__global__ void prep_waf(const float* __restrict__ w, unsigned short* __restrict__ waf) {
    int tid = blockIdx.x * 256 + threadIdx.x;
    if (tid < 72 * 512) {
        int slab = tid >> 9;           // 0..71
        int r = tid & 511;
        int l = r >> 3, j = r & 7;
        int m = slab & 3;
        int kc = (slab >> 2) & 1;
        int k = slab >> 3;
        int o = m * 16 + (l & 15);
        int i = k * 64 + kc * 32 + (l >> 4) * 8 + j;
        waf[tid] = f2bf(w[(size_t)o * II + i]);
    }
}

// ---------- main: per block one 16x16 output patch (256 px), window in LDS.
// 512 threads / 8 waves; wave w handles rows y0+2w, y0+2w+1 (2 n-tiles).
// Grid = 512 blocks = exactly 2 resident blocks per CU (72KB LDS each) -> no tail.
__global__ __launch_bounds__(512, 3) void deform_mfma6(
        const unsigned short* __restrict__ xt,   // [B][H][W][C] bf16
        const float* __restrict__ off,           // [B][2K][H][W]
        const unsigned short* __restrict__ waf,  // frag-ordered W, bf16
        const float* __restrict__ bias,          // [O]
        float* __restrict__ out) {               // [B][O][H][W]
    extern __shared__ unsigned short win[];      // WROWS * 64 shorts = 72KB

    const int blk = blockIdx.x;
    const int b = blk & 7;                 // XCD-ownership: image b on XCD b
    const int pidx = blk >> 3;             // 0..63
    const int y0 = (pidx >> 3) * PYH;      // 8 y-patches
    const int x0 = (pidx & 7) * PXW;       // 8 x-patches
    const int xleft = x0 - 4, ytop = y0 - 4;

    const int t = threadIdx.x;
    const int wave = t >> 6;               // 0..7
    const int lane = t & 63;
    const int fm = lane & 15;              // px-in-tile (B col)
    const int hi = lane >> 4;              // 0..3 (k-chunk)
    const int c0s = hi * 8;                // short offset, kc=0 chunk
    const int c1s = 32 + hi * 8;           // short offset, kc=1 chunk

    const unsigned short* xtb = xt + (size_t)b * HWSZ * CC;
    // per-lane offset source: pixel (y0+2w [+nt], x0+fm)
    const float* offpx = off + (size_t)b * 2 * KK * HWSZ
                             + (size_t)(y0 + wave * 2) * WWI + x0 + fm;

    // ---- issue tap-0 offset loads before the (long) window staging ----
    float oxb[2][2], oyb[2][2];            // [buf][nt], all indices compile-time
#pragma unroll
    for (int nt = 0; nt < 2; ++nt) {
        oxb[0][nt] = offpx[(size_t)0 * HWSZ + nt * WWI];
        oyb[0][nt] = offpx[(size_t)1 * HWSZ + nt * WWI];
    }

    // ---- stage window: rows (cy,cx) in [ytop,ytop+23] x [xleft,xleft+23] ----
    {
        const int tch = t & 7;             // 16B chunk within a row
        const int rb = t >> 3;             // 0..63
#pragma unroll
        for (int sw = 0; sw < 9; ++sw) {
            const int r = sw * 64 + rb;    // window row 0..575
            const int wy = r / WNX, wx = r - wy * WNX;
            const int cy = ytop + wy, cx = xleft + wx;
            if (((unsigned)cy < (unsigned)HH) && ((unsigned)cx < (unsigned)WWI)) {
                const uint4v v = *(const uint4v*)(xtb + (size_t)(cy * WWI + cx) * CC + tch * 8);
                *(uint4v*)&win[r * CC + ((tch ^ (r & 7)) << 3)] = v;  // swizzled
            }
        }
    }
    __syncthreads();

    f32x4 acc[2][4];
#pragma unroll
    for (int nt = 0; nt < 2; ++nt)
#pragma unroll
        for (int m = 0; m < 4; ++m) acc[nt][m] = (f32x4)(0.0f);

#pragma unroll
    for (int k = 0; k < KK; ++k) {
        const int cur = k & 1, nxt = cur ^ 1;
        if (k + 1 < KK) {                  // depth-1 offset prefetch
#pragma unroll
            for (int nt = 0; nt < 2; ++nt) {
                oxb[nxt][nt] = offpx[(size_t)(2 * k + 2) * HWSZ + nt * WWI];
                oyb[nxt][nt] = offpx[(size_t)(2 * k + 3) * HWSZ + nt * WWI];
            }
        }
        // A-fragments for tap k (reused by both n-tiles)
        const unsigned short* wk = waf + (size_t)k * 8 * 512 + lane * 8;
        bf16x8 af[8];
#pragma unroll
        for (int q = 0; q < 8; ++q) af[q] = *(const bf16x8*)(wk + (size_t)q * 512);

#pragma unroll
        for (int nt = 0; nt < 2; ++nt) {
            const float gx = oxb[cur][nt] + (float)(x0 + fm);        // padded coords
            const float gy = oyb[cur][nt] + (float)(y0 + wave * 2 + nt);
            const float fxf = floorf(gx), fyf = floorf(gy);
            const float fx = gx - fxf, fy = gy - fyf;
            const int ux0 = (int)fxf - 1, ux1 = (int)fxf;            // unpadded
            const int uy0 = (int)fyf - 1, uy1 = (int)fyf;
            const float vx0 = ((unsigned)ux0 < (unsigned)WWI) ? 1.0f : 0.0f;
            const float vx1 = ((unsigned)ux1 < (unsigned)WWI) ? 1.0f : 0.0f;
            const float vy0 = ((unsigned)uy0 < (unsigned)HH) ? 1.0f : 0.0f;
            const float vy1 = ((unsigned)uy1 < (unsigned)HH) ? 1.0f : 0.0f;
            const float w00 = (1.0f - fy) * (1.0f - fx) * vy0 * vx0;
            const float w01 = (1.0f - fy) * fx          * vy0 * vx1;
            const float w10 = fy          * (1.0f - fx) * vy1 * vx0;
            const float w11 = fy          * fx          * vy1 * vx1;
            const int cx0 = iclamp(ux0, 0, WWI - 1), cx1 = iclamp(ux1, 0, WWI - 1);
            const int cy0 = iclamp(uy0, 0, HH - 1),  cy1 = iclamp(uy1, 0, HH - 1);

            const bool inw = (cx0 >= xleft) & (cx1 <= xleft + WNX - 1)
                           & (cy0 >= ytop) & (cy1 <= ytop + WNY - 1);
            // window coords (clamped so LDS addrs stay in-bounds even when !inw)
            const int wx0 = iclamp(cx0 - xleft, 0, WNX - 1);
            const int wx1 = iclamp(cx1 - xleft, 0, WNX - 1);
            const int wy0 = iclamp(cy0 - ytop, 0, WNY - 1);
            const int wy1 = iclamp(cy1 - ytop, 0, WNY - 1);
            const int r00 = wy0 * WNX + wx0, r01 = wy0 * WNX + wx1;
            const int r10 = wy1 * WNX + wx0, r11 = wy1 * WNX + wx1;

            // 8 LDS corner reads (swizzled chunk slots: slot = (hi + kc*4) ^ (row&7))
#define LDSRD(r, kc) (*(const uint4v*)&win[(r) * CC + ((((hi) + ((kc) << 2)) ^ ((r) & 7)) << 3)])
            uint4v A0 = LDSRD(r00, 0), A1 = LDSRD(r00, 1);
            uint4v B0 = LDSRD(r01, 0), B1 = LDSRD(r01, 1);
            uint4v C0 = LDSRD(r10, 0), C1 = LDSRD(r10, 1);
            uint4v D0 = LDSRD(r11, 0), D1 = LDSRD(r11, 1);
#undef LDSRD
            if (!inw) {                    // rare (~0.05% of lanes): global fallback
                const unsigned short* g00 = xtb + (size_t)(cy0 * WWI + cx0) * CC;
                const unsigned short* g01 = xtb + (size_t)(cy0 * WWI + cx1) * CC;
                const unsigned short* g10 = xtb + (size_t)(cy1 * WWI + cx0) * CC;
                const unsigned short* g11 = xtb + (size_t)(cy1 * WWI + cx1) * CC;
                A0 = *(const uint4v*)(g00 + c0s);  A1 = *(const uint4v*)(g00 + c1s);
                B0 = *(const uint4v*)(g01 + c0s);  B1 = *(const uint4v*)(g01 + c1s);
                C0 = *(const uint4v*)(g10 + c0s);  C1 = *(const uint4v*)(g10 + c1s);
                D0 = *(const uint4v*)(g11 + c0s);  D1 = *(const uint4v*)(g11 + c1s);
            }

            // interpolate -> B-fragments (packed f32x2 math; lo/hi per u32)
            const f32x2 w00v = {w00, w00}, w01v = {w01, w01};
            const f32x2 w10v = {w10, w10}, w11v = {w11, w11};
            bf16x8 bf0, bf1;
            __hip_bfloat162* rp0 = (__hip_bfloat162*)&bf0;
            __hip_bfloat162* rp1 = (__hip_bfloat162*)&bf1;
#pragma unroll
            for (int i = 0; i < 4; ++i) {
                f32x2 r0 = unpk(A0[i]) * w00v;
                r0 += unpk(B0[i]) * w01v;
                r0 += unpk(C0[i]) * w10v;
                r0 += unpk(D0[i]) * w11v;
                rp0[i] = __hip_bfloat162{__float2bfloat16(r0.x), __float2bfloat16(r0.y)};
                f32x2 r1 = unpk(A1[i]) * w00v;
                r1 += unpk(B1[i]) * w01v;
                r1 += unpk(C1[i]) * w10v;
                r1 += unpk(D1[i]) * w11v;
                rp1[i] = __hip_bfloat162{__float2bfloat16(r1.x), __float2bfloat16(r1.y)};
            }
#pragma unroll
            for (int m = 0; m < 4; ++m)
                acc[nt][m] = __builtin_amdgcn_mfma_f32_16x16x32_bf16(af[m], bf0, acc[nt][m], 0, 0, 0);
#pragma unroll
            for (int m = 0; m < 4; ++m)
                acc[nt][m] = __builtin_amdgcn_mfma_f32_16x16x32_bf16(af[4 + m], bf1, acc[nt][m], 0, 0, 0);
        }
    }

    // epilogue: D col = fm (px), D row = hi*4 + j within m-tile -> o = m*16+hi*4+j
#pragma unroll
    for (int nt = 0; nt < 2; ++nt) {
        float* outb = out + (size_t)b * OO * HWSZ
                          + (size_t)(y0 + wave * 2 + nt) * WWI + x0 + fm;
#pragma unroll
        for (int m = 0; m < 4; ++m) {
            const int ob = m * 16 + hi * 4;
            const float4 bs = *(const float4*)(bias + ob);
#pragma unroll
            for (int j = 0; j < 4; ++j) {
                outb[(size_t)(ob + j) * HWSZ] = acc[nt][m][j] + ((const float*)&bs)[j];
            }
        }
    }
}

// ---------- fallback (round-1 fp32 path, used only if ws too small) ----------
__global__ __launch_bounds__(256) void deform_conv_fallback(
        const float* __restrict__ x, const float* __restrict__ off,
        const float* __restrict__ wmat, const float* __restrict__ bias,
        float* __restrict__ out) {
    const int b = blockIdx.y;
    const int p = blockIdx.x * 256 + threadIdx.x;
    const int wo = p & (WWI - 1);
    const int ho = p >> 7;
    const float* xb = x + (size_t)b * CC * HWSZ;
    const float* offb = off + (size_t)b * 2 * KK * HWSZ + p;
    float acc[OO];
#pragma unroll
    for (int o = 0; o < OO; ++o) acc[o] = 0.0f;
#pragma unroll 1
    for (int k = 0; k < KK; ++k) {
        const float gx = offb[(size_t)(2 * k + 0) * HWSZ] + (float)wo;
        const float gy = offb[(size_t)(2 * k + 1) * HWSZ] + (float)ho;
        const float fxf = floorf(gx), fyf = floorf(gy);
        const float fx = gx - fxf, fy = gy - fyf;
        const int ux0 = (int)fxf - 1, ux1 = (int)fxf;
        const int uy0 = (int)fyf - 1, uy1 = (int)fyf;
        const float vx0 = ((unsigned)ux0 < (unsigned)WWI) ? 1.0f : 0.0f;
        const float vx1 = ((unsigned)ux1 < (unsigned)WWI) ? 1.0f : 0.0f;
        const float vy0 = ((unsigned)uy0 < (unsigned)HH) ? 1.0f : 0.0f;
        const float vy1 = ((unsigned)uy1 < (unsigned)HH) ? 1.0f : 0.0f;
        const float w00 = (1.0f - fy) * (1.0f - fx) * vy0 * vx0;
        const float w01 = (1.0f - fy) * fx * vy0 * vx1;
        const float w10 = fy * (1.0f - fx) * vy1 * vx0;
        const float w11 = fy * fx * vy1 * vx1;
        const int cx0 = iclamp(ux0, 0, WWI - 1), cx1 = iclamp(ux1, 0, WWI - 1);
        const int cy0 = iclamp(uy0, 0, HH - 1), cy1 = iclamp(uy1, 0, HH - 1);
        const int i00 = cy0 * WWI + cx0, i01 = cy0 * WWI + cx1;
        const int i10 = cy1 * WWI + cx0, i11 = cy1 * WWI + cx1;
#pragma unroll 4
        for (int c = 0; c < CC; ++c) {
            const float* xc = xb + (size_t)c * HWSZ;
            const float v = w00 * xc[i00] + w01 * xc[i01] + w10 * xc[i10] + w11 * xc[i11];
            const float* wrow = wmat + (size_t)(k * CC + c);
#pragma unroll
            for (int o = 0; o < OO; ++o) acc[o] = fmaf(wrow[(size_t)o * II], v, acc[o]);
        }
    }
    float* outb = out + (size_t)b * OO * HWSZ + p;
#pragma unroll
    for (int o = 0; o < OO; ++o) outb[(size_t)o * HWSZ] = acc[o] + bias[o];
}

extern "C" void kernel_launch(void* const* d_in, const int* in_sizes, int n_in,
                              void* d_out, int out_size, void* d_ws, size_t ws_size,
                              hipStream_t stream) {
    const float* x    = (const float*)d_in[0];
    const float* off  = (const float*)d_in[1];
    const float* w    = (const float*)d_in[2];
    const float* bias = (const float*)d_in[3];
    float* out = (float*)d_out;

    const size_t xt_bytes  = (size_t)BB * HWSZ * CC * sizeof(unsigned short); // 16.78 MB
    const size_t waf_bytes = (size_t)72 * 512 * sizeof(unsigned short);       // 73728 B

    if (ws_size >= xt_bytes + waf_bytes) {
        unsigned short* xt  = (unsigned short*)d_ws;
        unsigned short* wfp = (unsigned short*)((char*)d_ws + xt_bytes);
        prep_xt<<<dim3((HWSZ / 64) * BB), 256, 0, stream>>>(x, xt);
        prep_waf<<<(72 * 512 + 255) / 256, 256, 0, stream>>>(w, wfp);
        // 8 images x (8 y-patches * 8 x-patches) = 512 blocks, 72KB dyn LDS
        deform_mfma6<<<dim3(BB * (HH / PYH) * (WWI / PXW)), dim3(512),
                       WROWS * CC * sizeof(unsigned short), stream>>>(
            xt, off, wfp, bias, out);
    } else {
        deform_conv_fallback<<<dim3(HWSZ / 256, BB), 256, 0, stream>>>(x, off, w, bias, out);
    }
}

// Round 9
// 50.910 us; speedup vs baseline: 1.0938x; 1.0938x over previous
//
#include <hip/hip_runtime.h>
#include <hip/hip_bf16.h>

// Problem constants
#define BB 8
#define CC 64
#define OO 64
#define HH 128
#define WWI 128
#define HWSZ (HH * WWI)     // 16384
#define KK 9                // 3x3 taps
#define II (KK * CC)        // 576

// patch / window geometry (main kernel)
#define PXW 16              // patch width  (x)
#define PYH 16              // patch height (y)
#define WNX 24              // window cols = PXW + 8
#define WNY 24              // window rows = PYH + 8
#define WROWS (WNX * WNY)   // 576 window rows, each 64 ch * 2B = 128B -> 72KB

typedef __attribute__((ext_vector_type(8))) _Float16 half8;
typedef __attribute__((ext_vector_type(2))) _Float16 h2;
typedef __attribute__((ext_vector_type(4))) float f32x4;
typedef __attribute__((ext_vector_type(4))) unsigned int uint4v;

__device__ __forceinline__ int iclamp(int v, int lo, int hi) {
    return v < lo ? lo : (v > hi ? hi : v);
}
__device__ __forceinline__ unsigned short f2h(float f) {
    union { _Float16 h; unsigned short s; } v;
    v.h = (_Float16)f;
    return v.s;
}
__device__ __forceinline__ h2 u2h(unsigned u) {
    union { unsigned u; h2 h; } v;
    v.u = u;
    return v.h;
}

// ---------- prep 1: x [B][C][H][W] f32 -> xt [B][H][W][C] fp16 (LDS transpose)
__global__ __launch_bounds__(256) void prep_xt(const float* __restrict__ x,
                                               unsigned short* __restrict__ xt) {
    __shared__ float tile[64][65];
    const int blk = blockIdx.x;
    const int b = blk & 7;
    const int p0 = (blk >> 3) * 64;
    const int t = threadIdx.x;
    const int a = t >> 6;   // 0..3
    const int q = t & 63;   // 0..63
    const float* xb = x + (size_t)b * CC * HWSZ + p0;
#pragma unroll
    for (int r = 0; r < 16; ++r) {
        int c = r * 4 + a;
        tile[c][q] = xb[(size_t)c * HWSZ + q];   // coalesced read
    }
    __syncthreads();
    unsigned short* xo = xt + ((size_t)b * HWSZ + p0) * CC;
#pragma unroll
    for (int r = 0; r < 16; ++r) {
        int pl = r * 4 + a;
        xo[(size_t)pl * CC + q] = f2h(tile[q][pl]);  // coalesced 2B x 64 write
    }
}

// ---------- prep 2: W -> fragment-ordered fp16 layout
// waf[slab][lane][j], slab = (k*2+kc)*4 + m, value =
//   W.flat[o = m*16+(lane&15)][i = k*64 + kc*32 + (lane>>4)*8 + j]
__global__ void prep_waf(const float* __restrict__ w, unsigned short* __restrict__ waf) {
    int tid = blockIdx.x * 256 + threadIdx.x;
    if (tid < 72 * 512) {
        int slab = tid >> 9;           // 0..71
        int r = tid & 511;
        int l = r >> 3, j = r & 7;
        int m = slab & 3;
        int kc = (slab >> 2) & 1;
        int k = slab >> 3;
        int o = m * 16 + (l & 15);
        int i = k * 64 + kc * 32 + (l >> 4) * 8 + j;
        waf[tid] = f2h(w[(size_t)o * II + i]);
    }
}

// ---------- main: per block one 16x16 output patch (256 px), window in LDS.
// 512 threads / 8 waves; wave w handles rows y0+2w, y0+2w+1 (2 n-tiles).
// fp16 data plane: interp via v_pk_fma_f16, MFMA f32_16x16x32_f16.
__global__ __launch_bounds__(512, 3) void deform_mfma7(
        const unsigned short* __restrict__ xt,   // [B][H][W][C] fp16
        const float* __restrict__ off,           // [B][2K][H][W]
        const unsigned short* __restrict__ waf,  // frag-ordered W, fp16
        const float* __restrict__ bias,          // [O]
        float* __restrict__ out) {               // [B][O][H][W]
    extern __shared__ unsigned short win[];      // WROWS * 64 shorts = 72KB

    const int blk = blockIdx.x;
    const int b = blk & 7;                 // XCD-ownership: image b on XCD b
    const int pidx = blk >> 3;             // 0..63
    const int y0 = (pidx >> 3) * PYH;      // 8 y-patches
    const int x0 = (pidx & 7) * PXW;       // 8 x-patches
    const int xleft = x0 - 4, ytop = y0 - 4;

    const int t = threadIdx.x;
    const int wave = t >> 6;               // 0..7
    const int lane = t & 63;
    const int fm = lane & 15;              // px-in-tile (B col)
    const int hi = lane >> 4;              // 0..3 (k-chunk)
    const int c0s = hi * 8;                // short offset, kc=0 chunk
    const int c1s = 32 + hi * 8;           // short offset, kc=1 chunk

    const unsigned short* xtb = xt + (size_t)b * HWSZ * CC;
    // per-lane offset source: pixel (y0+2w [+nt], x0+fm)
    const float* offpx = off + (size_t)b * 2 * KK * HWSZ
                             + (size_t)(y0 + wave * 2) * WWI + x0 + fm;

    // ---- issue tap-0 offset loads before the (long) window staging ----
    float oxb[2][2], oyb[2][2];            // [buf][nt], all indices compile-time
#pragma unroll
    for (int nt = 0; nt < 2; ++nt) {
        oxb[0][nt] = offpx[(size_t)0 * HWSZ + nt * WWI];
        oyb[0][nt] = offpx[(size_t)1 * HWSZ + nt * WWI];
    }

    // ---- stage window: rows (cy,cx) in [ytop,ytop+23] x [xleft,xleft+23] ----
    {
        const int tch = t & 7;             // 16B chunk within a row
        const int rb = t >> 3;             // 0..63
#pragma unroll
        for (int sw = 0; sw < 9; ++sw) {
            const int r = sw * 64 + rb;    // window row 0..575
            const int wy = r / WNX, wx = r - wy * WNX;
            const int cy = ytop + wy, cx = xleft + wx;
            if (((unsigned)cy < (unsigned)HH) && ((unsigned)cx < (unsigned)WWI)) {
                const uint4v v = *(const uint4v*)(xtb + (size_t)(cy * WWI + cx) * CC + tch * 8);
                *(uint4v*)&win[r * CC + ((tch ^ (r & 7)) << 3)] = v;  // swizzled
            }
        }
    }
    __syncthreads();

    f32x4 acc[2][4];
#pragma unroll
    for (int nt = 0; nt < 2; ++nt)
#pragma unroll
        for (int m = 0; m < 4; ++m) acc[nt][m] = (f32x4)(0.0f);

#pragma unroll
    for (int k = 0; k < KK; ++k) {
        const int cur = k & 1, nxt = cur ^ 1;
        if (k + 1 < KK) {                  // depth-1 offset prefetch
#pragma unroll
            for (int nt = 0; nt < 2; ++nt) {
                oxb[nxt][nt] = offpx[(size_t)(2 * k + 2) * HWSZ + nt * WWI];
                oyb[nxt][nt] = offpx[(size_t)(2 * k + 3) * HWSZ + nt * WWI];
            }
        }
        // A-fragments for tap k (reused by both n-tiles)
        const unsigned short* wk = waf + (size_t)k * 8 * 512 + lane * 8;
        half8 af[8];
#pragma unroll
        for (int q = 0; q < 8; ++q) af[q] = *(const half8*)(wk + (size_t)q * 512);

#pragma unroll
        for (int nt = 0; nt < 2; ++nt) {
            const float gx = oxb[cur][nt] + (float)(x0 + fm);        // padded coords
            const float gy = oyb[cur][nt] + (float)(y0 + wave * 2 + nt);
            const float fxf = floorf(gx), fyf = floorf(gy);
            const float fx = gx - fxf, fy = gy - fyf;
            const int ux0 = (int)fxf - 1, ux1 = (int)fxf;            // unpadded
            const int uy0 = (int)fyf - 1, uy1 = (int)fyf;
            const float vx0 = ((unsigned)ux0 < (unsigned)WWI) ? 1.0f : 0.0f;
            const float vx1 = ((unsigned)ux1 < (unsigned)WWI) ? 1.0f : 0.0f;
            const float vy0 = ((unsigned)uy0 < (unsigned)HH) ? 1.0f : 0.0f;
            const float vy1 = ((unsigned)uy1 < (unsigned)HH) ? 1.0f : 0.0f;
            const float w00 = (1.0f - fy) * (1.0f - fx) * vy0 * vx0;
            const float w01 = (1.0f - fy) * fx          * vy0 * vx1;
            const float w10 = fy          * (1.0f - fx) * vy1 * vx0;
            const float w11 = fy          * fx          * vy1 * vx1;
            const int cx0 = iclamp(ux0, 0, WWI - 1), cx1 = iclamp(ux1, 0, WWI - 1);
            const int cy0 = iclamp(uy0, 0, HH - 1),  cy1 = iclamp(uy1, 0, HH - 1);

            const bool inw = (cx0 >= xleft) & (cx1 <= xleft + WNX - 1)
                           & (cy0 >= ytop) & (cy1 <= ytop + WNY - 1);
            // window coords (clamped so LDS addrs stay in-bounds even when !inw)
            const int wx0 = iclamp(cx0 - xleft, 0, WNX - 1);
            const int wx1 = iclamp(cx1 - xleft, 0, WNX - 1);
            const int wy0 = iclamp(cy0 - ytop, 0, WNY - 1);
            const int wy1 = iclamp(cy1 - ytop, 0, WNY - 1);
            const int r00 = wy0 * WNX + wx0, r01 = wy0 * WNX + wx1;
            const int r10 = wy1 * WNX + wx0, r11 = wy1 * WNX + wx1;

            // 8 LDS corner reads (swizzled chunk slots: slot = (hi + kc*4) ^ (row&7))
#define LDSRD(r, kc) (*(const uint4v*)&win[(r) * CC + ((((hi) + ((kc) << 2)) ^ ((r) & 7)) << 3)])
            uint4v A0 = LDSRD(r00, 0), A1 = LDSRD(r00, 1);
            uint4v B0 = LDSRD(r01, 0), B1 = LDSRD(r01, 1);
            uint4v C0 = LDSRD(r10, 0), C1 = LDSRD(r10, 1);
            uint4v D0 = LDSRD(r11, 0), D1 = LDSRD(r11, 1);
#undef LDSRD
            if (!inw) {                    // rare (~0.05% of lanes): global fallback
                const unsigned short* g00 = xtb + (size_t)(cy0 * WWI + cx0) * CC;
                const unsigned short* g01 = xtb + (size_t)(cy0 * WWI + cx1) * CC;
                const unsigned short* g10 = xtb + (size_t)(cy1 * WWI + cx0) * CC;
                const unsigned short* g11 = xtb + (size_t)(cy1 * WWI + cx1) * CC;
                A0 = *(const uint4v*)(g00 + c0s);  A1 = *(const uint4v*)(g00 + c1s);
                B0 = *(const uint4v*)(g01 + c0s);  B1 = *(const uint4v*)(g01 + c1s);
                C0 = *(const uint4v*)(g10 + c0s);  C1 = *(const uint4v*)(g10 + c1s);
                D0 = *(const uint4v*)(g11 + c0s);  D1 = *(const uint4v*)(g11 + c1s);
            }

            // interpolate in packed fp16 (v_pk_fma_f16): result IS the B-frag
            const _Float16 hw00 = (_Float16)w00, hw01 = (_Float16)w01;
            const _Float16 hw10 = (_Float16)w10, hw11 = (_Float16)w11;
            const h2 w00v = {hw00, hw00}, w01v = {hw01, hw01};
            const h2 w10v = {hw10, hw10}, w11v = {hw11, hw11};
            half8 bf0, bf1;
            h2* rp0 = (h2*)&bf0;
            h2* rp1 = (h2*)&bf1;
#pragma unroll
            for (int i = 0; i < 4; ++i) {
                h2 r0 = u2h(A0[i]) * w00v;
                r0 += u2h(B0[i]) * w01v;
                r0 += u2h(C0[i]) * w10v;
                r0 += u2h(D0[i]) * w11v;
                rp0[i] = r0;
                h2 r1 = u2h(A1[i]) * w00v;
                r1 += u2h(B1[i]) * w01v;
                r1 += u2h(C1[i]) * w10v;
                r1 += u2h(D1[i]) * w11v;
                rp1[i] = r1;
            }
#pragma unroll
            for (int m = 0; m < 4; ++m)
                acc[nt][m] = __builtin_amdgcn_mfma_f32_16x16x32_f16(af[m], bf0, acc[nt][m], 0, 0, 0);
#pragma unroll
            for (int m = 0; m < 4; ++m)
                acc[nt][m] = __builtin_amdgcn_mfma_f32_16x16x32_f16(af[4 + m], bf1, acc[nt][m], 0, 0, 0);
        }
    }

    // epilogue: D col = fm (px), D row = hi*4 + j within m-tile -> o = m*16+hi*4+j
#pragma unroll
    for (int nt = 0; nt < 2; ++nt) {
        float* outb = out + (size_t)b * OO * HWSZ
                          + (size_t)(y0 + wave * 2 + nt) * WWI + x0 + fm;
#pragma unroll
        for (int m = 0; m < 4; ++m) {
            const int ob = m * 16 + hi * 4;
            const float4 bs = *(const float4*)(bias + ob);
#pragma unroll
            for (int j = 0; j < 4; ++j) {
                outb[(size_t)(ob + j) * HWSZ] = acc[nt][m][j] + ((const float*)&bs)[j];
            }
        }
    }
}

// ---------- fallback (round-1 fp32 path, used only if ws too small) ----------
__global__ __launch_bounds__(256) void deform_conv_fallback(
        const float* __restrict__ x, const float* __restrict__ off,
        const float* __restrict__ wmat, const float* __restrict__ bias,
        float* __restrict__ out) {
    const int b = blockIdx.y;
    const int p = blockIdx.x * 256 + threadIdx.x;
    const int wo = p & (WWI - 1);
    const int ho = p >> 7;
    const float* xb = x + (size_t)b * CC * HWSZ;
    const float* offb = off + (size_t)b * 2 * KK * HWSZ + p;
    float acc[OO];
#pragma unroll
    for (int o = 0; o < OO; ++o) acc[o] = 0.0f;
#pragma unroll 1
    for (int k = 0; k < KK; ++k) {
        const float gx = offb[(size_t)(2 * k + 0) * HWSZ] + (float)wo;
        const float gy = offb[(size_t)(2 * k + 1) * HWSZ] + (float)ho;
        const float fxf = floorf(gx), fyf = floorf(gy);
        const float fx = gx - fxf, fy = gy - fyf;
        const int ux0 = (int)fxf - 1, ux1 = (int)fxf;
        const int uy0 = (int)fyf - 1, uy1 = (int)fyf;
        const float vx0 = ((unsigned)ux0 < (unsigned)WWI) ? 1.0f : 0.0f;
        const float vx1 = ((unsigned)ux1 < (unsigned)WWI) ? 1.0f : 0.0f;
        const float vy0 = ((unsigned)uy0 < (unsigned)HH) ? 1.0f : 0.0f;
        const float vy1 = ((unsigned)uy1 < (unsigned)HH) ? 1.0f : 0.0f;
        const float w00 = (1.0f - fy) * (1.0f - fx) * vy0 * vx0;
        const float w01 = (1.0f - fy) * fx * vy0 * vx1;
        const float w10 = fy * (1.0f - fx) * vy1 * vx0;
        const float w11 = fy * fx * vy1 * vx1;
        const int cx0 = iclamp(ux0, 0, WWI - 1), cx1 = iclamp(ux1, 0, WWI - 1);
        const int cy0 = iclamp(uy0, 0, HH - 1), cy1 = iclamp(uy1, 0, HH - 1);
        const int i00 = cy0 * WWI + cx0, i01 = cy0 * WWI + cx1;
        const int i10 = cy1 * WWI + cx0, i11 = cy1 * WWI + cx1;
#pragma unroll 4
        for (int c = 0; c < CC; ++c) {
            const float* xc = xb + (size_t)c * HWSZ;
            const float v = w00 * xc[i00] + w01 * xc[i01] + w10 * xc[i10] + w11 * xc[i11];
            const float* wrow = wmat + (size_t)(k * CC + c);
#pragma unroll
            for (int o = 0; o < OO; ++o) acc[o] = fmaf(wrow[(size_t)o * II], v, acc[o]);
        }
    }
    float* outb = out + (size_t)b * OO * HWSZ + p;
#pragma unroll
    for (int o = 0; o < OO; ++o) outb[(size_t)o * HWSZ] = acc[o] + bias[o];
}

extern "C" void kernel_launch(void* const* d_in, const int* in_sizes, int n_in,
                              void* d_out, int out_size, void* d_ws, size_t ws_size,
                              hipStream_t stream) {
    const float* x    = (const float*)d_in[0];
    const float* off  = (const float*)d_in[1];
    const float* w    = (const float*)d_in[2];
    const float* bias = (const float*)d_in[3];
    float* out = (float*)d_out;

    const size_t xt_bytes  = (size_t)BB * HWSZ * CC * sizeof(unsigned short); // 16.78 MB
    const size_t waf_bytes = (size_t)72 * 512 * sizeof(unsigned short);       // 73728 B

    if (ws_size >= xt_bytes + waf_bytes) {
        unsigned short* xt  = (unsigned short*)d_ws;
        unsigned short* wfp = (unsigned short*)((char*)d_ws + xt_bytes);
        prep_xt<<<dim3((HWSZ / 64) * BB), 256, 0, stream>>>(x, xt);
        prep_waf<<<(72 * 512 + 255) / 256, 256, 0, stream>>>(w, wfp);
        // 8 images x (8 y-patches * 8 x-patches) = 512 blocks, 72KB dyn LDS
        deform_mfma7<<<dim3(BB * (HH / PYH) * (WWI / PXW)), dim3(512),
                       WROWS * CC * sizeof(unsigned short), stream>>>(
            xt, off, wfp, bias, out);
    } else {
        deform_conv_fallback<<<dim3(HWSZ / 256, BB), 256, 0, stream>>>(x, off, w, bias, out);
    }
}

// Round 10
// 50.647 us; speedup vs baseline: 1.0995x; 1.0052x over previous
//
#include <hip/hip_runtime.h>
#include <hip/hip_bf16.h>

// Problem constants
#define BB 8
#define CC 64
#define OO 64
#define HH 128
#define WWI 128
#define HWSZ (HH * WWI)     // 16384
#define KK 9                // 3x3 taps
#define II (KK * CC)        // 576

// patch / window geometry (main kernel)
#define PXW 32              // patch width  (x)
#define PYH 16              // patch height (y)
#define WNX 40              // window cols = PXW + 8
#define WNY 24              // window rows = PYH + 8
#define WROWS (WNX * WNY)   // 960 window rows, each 64 ch * 2B = 128B -> 120KB

typedef __attribute__((ext_vector_type(8))) _Float16 half8;
typedef __attribute__((ext_vector_type(2))) _Float16 h2;
typedef __attribute__((ext_vector_type(4))) float f32x4;
typedef __attribute__((ext_vector_type(4))) unsigned int uint4v;

__device__ __forceinline__ int iclamp(int v, int lo, int hi) {
    return v < lo ? lo : (v > hi ? hi : v);
}
__device__ __forceinline__ unsigned short f2h(float f) {
    union { _Float16 h; unsigned short s; } v;
    v.h = (_Float16)f;
    return v.s;
}
__device__ __forceinline__ h2 u2h(unsigned u) {
    union { unsigned u; h2 h; } v;
    v.u = u;
    return v.h;
}

// ---------- prep 1: x [B][C][H][W] f32 -> xt [B][H][W][C] fp16 (LDS transpose)
__global__ __launch_bounds__(256) void prep_xt(const float* __restrict__ x,
                                               unsigned short* __restrict__ xt) {
    __shared__ float tile[64][65];
    const int blk = blockIdx.x;
    const int b = blk & 7;
    const int p0 = (blk >> 3) * 64;
    const int t = threadIdx.x;
    const int a = t >> 6;   // 0..3
    const int q = t & 63;   // 0..63
    const float* xb = x + (size_t)b * CC * HWSZ + p0;
#pragma unroll
    for (int r = 0; r < 16; ++r) {
        int c = r * 4 + a;
        tile[c][q] = xb[(size_t)c * HWSZ + q];   // coalesced read
    }
    __syncthreads();
    unsigned short* xo = xt + ((size_t)b * HWSZ + p0) * CC;
#pragma unroll
    for (int r = 0; r < 16; ++r) {
        int pl = r * 4 + a;
        xo[(size_t)pl * CC + q] = f2h(tile[q][pl]);  // coalesced 2B x 64 write
    }
}

// ---------- prep 2: W -> fragment-ordered fp16 layout
// waf[slab][lane][j], slab = (k*2+kc)*4 + m, value =
//   W.flat[o = m*16+(lane&15)][i = k*64 + kc*32 + (lane>>4)*8 + j]
__global__ void prep_waf(const float* __restrict__ w, unsigned short* __restrict__ waf) {
    int tid = blockIdx.x * 256 + threadIdx.x;
    if (tid < 72 * 512) {
        int slab = tid >> 9;           // 0..71
        int r = tid & 511;
        int l = r >> 3, j = r & 7;
        int m = slab & 3;
        int kc = (slab >> 2) & 1;
        int k = slab >> 3;
        int o = m * 16 + (l & 15);
        int i = k * 64 + kc * 32 + (l >> 4) * 8 + j;
        waf[tid] = f2h(w[(size_t)o * II + i]);
    }
}

// ---------- main: per block one 32x16 output patch (512 px), window in LDS.
// 1024 threads / 16 waves; wave w owns row y0+w, two 16-px n-tiles along x.
// Grid = 256 blocks = exactly 1 block per CU (120KB LDS) -> no tail, 4 waves/SIMD.
__global__ __launch_bounds__(1024, 4) void deform_mfma8(
        const unsigned short* __restrict__ xt,   // [B][H][W][C] fp16
        const float* __restrict__ off,           // [B][2K][H][W]
        const unsigned short* __restrict__ waf,  // frag-ordered W, fp16
        const float* __restrict__ bias,          // [O]
        float* __restrict__ out) {               // [B][O][H][W]
    extern __shared__ unsigned short win[];      // WROWS * 64 shorts = 120KB

    const int blk = blockIdx.x;
    const int b = blk & 7;                 // XCD-ownership: image b on XCD b
    const int pidx = blk >> 3;             // 0..31
    const int y0 = (pidx >> 2) * PYH;      // 8 y-patches
    const int x0 = (pidx & 3) * PXW;       // 4 x-patches
    const int xleft = x0 - 4, ytop = y0 - 4;

    const int t = threadIdx.x;
    const int wave = t >> 6;               // 0..15
    const int lane = t & 63;
    const int fm = lane & 15;              // px-in-tile (B col)
    const int hi = lane >> 4;              // 0..3 (k-chunk)
    const int c0s = hi * 8;                // short offset, kc=0 chunk
    const int c1s = 32 + hi * 8;           // short offset, kc=1 chunk

    const unsigned short* xtb = xt + (size_t)b * HWSZ * CC;
    // per-lane offset source: pixel (y0+wave, x0 + nt*16 + fm)
    const float* offpx = off + (size_t)b * 2 * KK * HWSZ
                             + (size_t)(y0 + wave) * WWI + x0 + fm;

    // ---- issue tap-0 offset loads before the (long) window staging ----
    float oxb[2][2], oyb[2][2];            // [buf][nt], all indices compile-time
#pragma unroll
    for (int nt = 0; nt < 2; ++nt) {
        oxb[0][nt] = offpx[(size_t)0 * HWSZ + nt * 16];
        oyb[0][nt] = offpx[(size_t)1 * HWSZ + nt * 16];
    }

    // ---- stage window: rows (cy,cx) in [ytop,ytop+23] x [xleft,xleft+39] ----
    {
        const int tch = t & 7;             // 16B chunk within a row
        const int rb = t >> 3;             // 0..127
#pragma unroll
        for (int sw = 0; sw < 8; ++sw) {
            const int r = sw * 128 + rb;   // window row 0..959
            if (r < WROWS) {
                const int wy = r / WNX, wx = r - wy * WNX;
                const int cy = ytop + wy, cx = xleft + wx;
                if (((unsigned)cy < (unsigned)HH) && ((unsigned)cx < (unsigned)WWI)) {
                    const uint4v v = *(const uint4v*)(xtb + (size_t)(cy * WWI + cx) * CC + tch * 8);
                    *(uint4v*)&win[r * CC + ((tch ^ (r & 7)) << 3)] = v;  // swizzled
                }
            }
        }
    }
    __syncthreads();

    f32x4 acc[2][4];
#pragma unroll
    for (int nt = 0; nt < 2; ++nt)
#pragma unroll
        for (int m = 0; m < 4; ++m) acc[nt][m] = (f32x4)(0.0f);

#pragma unroll
    for (int k = 0; k < KK; ++k) {
        const int cur = k & 1, nxt = cur ^ 1;
        if (k + 1 < KK) {                  // depth-1 offset prefetch
#pragma unroll
            for (int nt = 0; nt < 2; ++nt) {
                oxb[nxt][nt] = offpx[(size_t)(2 * k + 2) * HWSZ + nt * 16];
                oyb[nxt][nt] = offpx[(size_t)(2 * k + 3) * HWSZ + nt * 16];
            }
        }
        // A-fragments for tap k (reused by both n-tiles)
        const unsigned short* wk = waf + (size_t)k * 8 * 512 + lane * 8;
        half8 af[8];
#pragma unroll
        for (int q = 0; q < 8; ++q) af[q] = *(const half8*)(wk + (size_t)q * 512);

#pragma unroll
        for (int nt = 0; nt < 2; ++nt) {
            const float gx = oxb[cur][nt] + (float)(x0 + nt * 16 + fm);  // padded
            const float gy = oyb[cur][nt] + (float)(y0 + wave);
            const float fxf = floorf(gx), fyf = floorf(gy);
            const float fx = gx - fxf, fy = gy - fyf;
            const int ux0 = (int)fxf - 1, ux1 = (int)fxf;            // unpadded
            const int uy0 = (int)fyf - 1, uy1 = (int)fyf;
            const float vx0 = ((unsigned)ux0 < (unsigned)WWI) ? 1.0f : 0.0f;
            const float vx1 = ((unsigned)ux1 < (unsigned)WWI) ? 1.0f : 0.0f;
            const float vy0 = ((unsigned)uy0 < (unsigned)HH) ? 1.0f : 0.0f;
            const float vy1 = ((unsigned)uy1 < (unsigned)HH) ? 1.0f : 0.0f;
            const float w00 = (1.0f - fy) * (1.0f - fx) * vy0 * vx0;
            const float w01 = (1.0f - fy) * fx          * vy0 * vx1;
            const float w10 = fy          * (1.0f - fx) * vy1 * vx0;
            const float w11 = fy          * fx          * vy1 * vx1;
            const int cx0 = iclamp(ux0, 0, WWI - 1), cx1 = iclamp(ux1, 0, WWI - 1);
            const int cy0 = iclamp(uy0, 0, HH - 1),  cy1 = iclamp(uy1, 0, HH - 1);

            const bool inw = (cx0 >= xleft) & (cx1 <= xleft + WNX - 1)
                           & (cy0 >= ytop) & (cy1 <= ytop + WNY - 1);
            // window coords (clamped so LDS addrs stay in-bounds even when !inw)
            const int wx0 = iclamp(cx0 - xleft, 0, WNX - 1);
            const int wx1 = iclamp(cx1 - xleft, 0, WNX - 1);
            const int wy0 = iclamp(cy0 - ytop, 0, WNY - 1);
            const int wy1 = iclamp(cy1 - ytop, 0, WNY - 1);
            const int r00 = wy0 * WNX + wx0, r01 = wy0 * WNX + wx1;
            const int r10 = wy1 * WNX + wx0, r11 = wy1 * WNX + wx1;

            // 8 LDS corner reads (swizzled chunk slots: slot = (hi + kc*4) ^ (row&7))
#define LDSRD(r, kc) (*(const uint4v*)&win[(r) * CC + ((((hi) + ((kc) << 2)) ^ ((r) & 7)) << 3)])
            uint4v A0 = LDSRD(r00, 0), A1 = LDSRD(r00, 1);
            uint4v B0 = LDSRD(r01, 0), B1 = LDSRD(r01, 1);
            uint4v C0 = LDSRD(r10, 0), C1 = LDSRD(r10, 1);
            uint4v D0 = LDSRD(r11, 0), D1 = LDSRD(r11, 1);
#undef LDSRD
            if (!inw) {                    // rare (~0.05% of lanes): global fallback
                const unsigned short* g00 = xtb + (size_t)(cy0 * WWI + cx0) * CC;
                const unsigned short* g01 = xtb + (size_t)(cy0 * WWI + cx1) * CC;
                const unsigned short* g10 = xtb + (size_t)(cy1 * WWI + cx0) * CC;
                const unsigned short* g11 = xtb + (size_t)(cy1 * WWI + cx1) * CC;
                A0 = *(const uint4v*)(g00 + c0s);  A1 = *(const uint4v*)(g00 + c1s);
                B0 = *(const uint4v*)(g01 + c0s);  B1 = *(const uint4v*)(g01 + c1s);
                C0 = *(const uint4v*)(g10 + c0s);  C1 = *(const uint4v*)(g10 + c1s);
                D0 = *(const uint4v*)(g11 + c0s);  D1 = *(const uint4v*)(g11 + c1s);
            }

            // interpolate in packed fp16 (v_pk_fma_f16): result IS the B-frag
            const _Float16 hw00 = (_Float16)w00, hw01 = (_Float16)w01;
            const _Float16 hw10 = (_Float16)w10, hw11 = (_Float16)w11;
            const h2 w00v = {hw00, hw00}, w01v = {hw01, hw01};
            const h2 w10v = {hw10, hw10}, w11v = {hw11, hw11};
            half8 bf0, bf1;
            h2* rp0 = (h2*)&bf0;
            h2* rp1 = (h2*)&bf1;
#pragma unroll
            for (int i = 0; i < 4; ++i) {
                h2 r0 = u2h(A0[i]) * w00v;
                r0 += u2h(B0[i]) * w01v;
                r0 += u2h(C0[i]) * w10v;
                r0 += u2h(D0[i]) * w11v;
                rp0[i] = r0;
                h2 r1 = u2h(A1[i]) * w00v;
                r1 += u2h(B1[i]) * w01v;
                r1 += u2h(C1[i]) * w10v;
                r1 += u2h(D1[i]) * w11v;
                rp1[i] = r1;
            }
#pragma unroll
            for (int m = 0; m < 4; ++m)
                acc[nt][m] = __builtin_amdgcn_mfma_f32_16x16x32_f16(af[m], bf0, acc[nt][m], 0, 0, 0);
#pragma unroll
            for (int m = 0; m < 4; ++m)
                acc[nt][m] = __builtin_amdgcn_mfma_f32_16x16x32_f16(af[4 + m], bf1, acc[nt][m], 0, 0, 0);
        }
    }

    // epilogue: D col = fm (px), D row = hi*4 + j within m-tile -> o = m*16+hi*4+j
#pragma unroll
    for (int nt = 0; nt < 2; ++nt) {
        float* outb = out + (size_t)b * OO * HWSZ
                          + (size_t)(y0 + wave) * WWI + x0 + nt * 16 + fm;
#pragma unroll
        for (int m = 0; m < 4; ++m) {
            const int ob = m * 16 + hi * 4;
            const float4 bs = *(const float4*)(bias + ob);
#pragma unroll
            for (int j = 0; j < 4; ++j) {
                outb[(size_t)(ob + j) * HWSZ] = acc[nt][m][j] + ((const float*)&bs)[j];
            }
        }
    }
}

// ---------- fallback (round-1 fp32 path, used only if ws too small) ----------
__global__ __launch_bounds__(256) void deform_conv_fallback(
        const float* __restrict__ x, const float* __restrict__ off,
        const float* __restrict__ wmat, const float* __restrict__ bias,
        float* __restrict__ out) {
    const int b = blockIdx.y;
    const int p = blockIdx.x * 256 + threadIdx.x;
    const int wo = p & (WWI - 1);
    const int ho = p >> 7;
    const float* xb = x + (size_t)b * CC * HWSZ;
    const float* offb = off + (size_t)b * 2 * KK * HWSZ + p;
    float acc[OO];
#pragma unroll
    for (int o = 0; o < OO; ++o) acc[o] = 0.0f;
#pragma unroll 1
    for (int k = 0; k < KK; ++k) {
        const float gx = offb[(size_t)(2 * k + 0) * HWSZ] + (float)wo;
        const float gy = offb[(size_t)(2 * k + 1) * HWSZ] + (float)ho;
        const float fxf = floorf(gx), fyf = floorf(gy);
        const float fx = gx - fxf, fy = gy - fyf;
        const int ux0 = (int)fxf - 1, ux1 = (int)fxf;
        const int uy0 = (int)fyf - 1, uy1 = (int)fyf;
        const float vx0 = ((unsigned)ux0 < (unsigned)WWI) ? 1.0f : 0.0f;
        const float vx1 = ((unsigned)ux1 < (unsigned)WWI) ? 1.0f : 0.0f;
        const float vy0 = ((unsigned)uy0 < (unsigned)HH) ? 1.0f : 0.0f;
        const float vy1 = ((unsigned)uy1 < (unsigned)HH) ? 1.0f : 0.0f;
        const float w00 = (1.0f - fy) * (1.0f - fx) * vy0 * vx0;
        const float w01 = (1.0f - fy) * fx * vy0 * vx1;
        const float w10 = fy * (1.0f - fx) * vy1 * vx0;
        const float w11 = fy * fx * vy1 * vx1;
        const int cx0 = iclamp(ux0, 0, WWI - 1), cx1 = iclamp(ux1, 0, WWI - 1);
        const int cy0 = iclamp(uy0, 0, HH - 1), cy1 = iclamp(uy1, 0, HH - 1);
        const int i00 = cy0 * WWI + cx0, i01 = cy0 * WWI + cx1;
        const int i10 = cy1 * WWI + cx0, i11 = cy1 * WWI + cx1;
#pragma unroll 4
        for (int c = 0; c < CC; ++c) {
            const float* xc = xb + (size_t)c * HWSZ;
            const float v = w00 * xc[i00] + w01 * xc[i01] + w10 * xc[i10] + w11 * xc[i11];
            const float* wrow = wmat + (size_t)(k * CC + c);
#pragma unroll
            for (int o = 0; o < OO; ++o) acc[o] = fmaf(wrow[(size_t)o * II], v, acc[o]);
        }
    }
    float* outb = out + (size_t)b * OO * HWSZ + p;
#pragma unroll
    for (int o = 0; o < OO; ++o) outb[(size_t)o * HWSZ] = acc[o] + bias[o];
}

extern "C" void kernel_launch(void* const* d_in, const int* in_sizes, int n_in,
                              void* d_out, int out_size, void* d_ws, size_t ws_size,
                              hipStream_t stream) {
    const float* x    = (const float*)d_in[0];
    const float* off  = (const float*)d_in[1];
    const float* w    = (const float*)d_in[2];
    const float* bias = (const float*)d_in[3];
    float* out = (float*)d_out;

    const size_t xt_bytes  = (size_t)BB * HWSZ * CC * sizeof(unsigned short); // 16.78 MB
    const size_t waf_bytes = (size_t)72 * 512 * sizeof(unsigned short);       // 73728 B

    if (ws_size >= xt_bytes + waf_bytes) {
        unsigned short* xt  = (unsigned short*)d_ws;
        unsigned short* wfp = (unsigned short*)((char*)d_ws + xt_bytes);
        prep_xt<<<dim3((HWSZ / 64) * BB), 256, 0, stream>>>(x, xt);
        prep_waf<<<(72 * 512 + 255) / 256, 256, 0, stream>>>(w, wfp);
        // 8 images x (8 y-patches * 4 x-patches) = 256 blocks, 120KB dyn LDS
        deform_mfma8<<<dim3(BB * (HH / PYH) * (WWI / PXW)), dim3(1024),
                       WROWS * CC * sizeof(unsigned short), stream>>>(
            xt, off, wfp, bias, out);
    } else {
        deform_conv_fallback<<<dim3(HWSZ / 256, BB), 256, 0, stream>>>(x, off, w, bias, out);
    }
}

// Round 11
// 46.539 us; speedup vs baseline: 1.1965x; 1.0883x over previous
//
#include <hip/hip_runtime.h>
#include <hip/hip_bf16.h>

// Problem constants
#define BB 8
#define CC 64
#define OO 64
#define HH 128
#define WWI 128
#define HWSZ (HH * WWI)     // 16384
#define KK 9                // 3x3 taps
#define II (KK * CC)        // 576

// patch / window geometry (main kernel)
#define PXW 16              // patch width  (x)
#define PYH 16              // patch height (y)
#define WNX 24              // window cols = PXW + 8
#define WNY 24              // window rows = PYH + 8
#define WROWS (WNX * WNY)   // 576 window rows, each 64 ch * 2B = 128B -> 72KB

typedef __attribute__((ext_vector_type(8))) _Float16 half8;
typedef __attribute__((ext_vector_type(2))) _Float16 h2;
typedef __attribute__((ext_vector_type(4))) float f32x4;
typedef __attribute__((ext_vector_type(4))) unsigned int uint4v;

__device__ __forceinline__ int iclamp(int v, int lo, int hi) {
    return v < lo ? lo : (v > hi ? hi : v);
}
__device__ __forceinline__ unsigned short f2h(float f) {
    union { _Float16 h; unsigned short s; } v;
    v.h = (_Float16)f;
    return v.s;
}
__device__ __forceinline__ h2 u2h(unsigned u) {
    union { unsigned u; h2 h; } v;
    v.u = u;
    return v.h;
}

// ---------- prep 1: x [B][C][H][W] f32 -> xt [B][H][W][C] fp16 (LDS transpose)
__global__ __launch_bounds__(256) void prep_xt(const float* __restrict__ x,
                                               unsigned short* __restrict__ xt) {
    __shared__ float tile[64][65];
    const int blk = blockIdx.x;
    const int b = blk & 7;
    const int p0 = (blk >> 3) * 64;
    const int t = threadIdx.x;
    const int a = t >> 6;   // 0..3
    const int q = t & 63;   // 0..63
    const float* xb = x + (size_t)b * CC * HWSZ + p0;
#pragma unroll
    for (int r = 0; r < 16; ++r) {
        int c = r * 4 + a;
        tile[c][q] = xb[(size_t)c * HWSZ + q];   // coalesced read
    }
    __syncthreads();
    unsigned short* xo = xt + ((size_t)b * HWSZ + p0) * CC;
#pragma unroll
    for (int r = 0; r < 16; ++r) {
        int pl = r * 4 + a;
        xo[(size_t)pl * CC + q] = f2h(tile[q][pl]);  // coalesced 2B x 64 write
    }
}

// ---------- prep 2: W -> fragment-ordered fp16 layout
// waf[slab][lane][j], slab = (k*2+kc)*4 + m, value =
//   W.flat[o = m*16+(lane&15)][i = k*64 + kc*32 + (lane>>4)*8 + j]
__global__ void prep_waf(const float* __restrict__ w, unsigned short* __restrict__ waf) {
    int tid = blockIdx.x * 256 + threadIdx.x;
    if (tid < 72 * 512) {
        int slab = tid >> 9;           // 0..71
        int r = tid & 511;
        int l = r >> 3, j = r & 7;
        int m = slab & 3;
        int kc = (slab >> 2) & 1;
        int k = slab >> 3;
        int o = m * 16 + (l & 15);
        int i = k * 64 + kc * 32 + (l >> 4) * 8 + j;
        waf[tid] = f2h(w[(size_t)o * II + i]);
    }
}

// ---------- main: 16x16 patch per block, window in LDS, 8 waves.
// Explicit depth-2 (tap,nt)-unit software pipeline with asm-pinned ds_reads.
// __launch_bounds__(512,2): VGPR cap 256 so the whole pipeline lives in regs.
__global__ __launch_bounds__(512, 2) void deform_mfma9(
        const unsigned short* __restrict__ xt,   // [B][H][W][C] fp16
        const float* __restrict__ off,           // [B][2K][H][W]
        const unsigned short* __restrict__ waf,  // frag-ordered W, fp16
        const float* __restrict__ bias,          // [O]
        float* __restrict__ out) {               // [B][O][H][W]
    extern __shared__ unsigned short win[];      // WROWS * 64 shorts = 72KB

    const int blk = blockIdx.x;
    const int b = blk & 7;                 // XCD-ownership: image b on XCD b
    const int pidx = blk >> 3;             // 0..63
    const int y0 = (pidx >> 3) * PYH;      // 8 y-patches
    const int x0 = (pidx & 7) * PXW;       // 8 x-patches
    const int xleft = x0 - 4, ytop = y0 - 4;

    const int t = threadIdx.x;
    const int wave = t >> 6;               // 0..7
    const int lane = t & 63;
    const int fm = lane & 15;              // px-in-tile (B col)
    const int hi = lane >> 4;              // 0..3 (k-chunk)
    const int c0s = hi * 8;                // short offset, kc=0 chunk
    const int c1s = 32 + hi * 8;           // short offset, kc=1 chunk

    const unsigned short* xtb = xt + (size_t)b * HWSZ * CC;
    // per-lane offset source: pixel (y0+2w [+nt], x0+fm)
    const float* offpx = off + (size_t)b * 2 * KK * HWSZ
                             + (size_t)(y0 + wave * 2) * WWI + x0 + fm;

    // 3-slot offset ring (slot = tap%3); preload taps 0,1 before staging
    float ox[3][2], oy[3][2];
#pragma unroll
    for (int k = 0; k < 2; ++k) {
#pragma unroll
        for (int nt = 0; nt < 2; ++nt) {
            ox[k][nt] = offpx[(size_t)(2 * k + 0) * HWSZ + nt * WWI];
            oy[k][nt] = offpx[(size_t)(2 * k + 1) * HWSZ + nt * WWI];
        }
    }

    // ---- stage window: rows (cy,cx) in [ytop,ytop+23] x [xleft,xleft+23] ----
    {
        const int tch = t & 7;             // 16B chunk within a row
        const int rb = t >> 3;             // 0..63
#pragma unroll
        for (int sw = 0; sw < 9; ++sw) {
            const int r = sw * 64 + rb;    // window row 0..575
            const int wy = r / WNX, wx = r - wy * WNX;
            const int cy = ytop + wy, cx = xleft + wx;
            if (((unsigned)cy < (unsigned)HH) && ((unsigned)cx < (unsigned)WWI)) {
                const uint4v v = *(const uint4v*)(xtb + (size_t)(cy * WWI + cx) * CC + tch * 8);
                *(uint4v*)&win[r * CC + ((tch ^ (r & 7)) << 3)] = v;  // swizzled
            }
        }
    }
    __syncthreads();

    f32x4 acc[2][4];
#pragma unroll
    for (int nt = 0; nt < 2; ++nt)
#pragma unroll
        for (int m = 0; m < 4; ++m) acc[nt][m] = (f32x4)(0.0f);

    // pipeline state (all indices compile-time constants after macro expansion)
    uint4v cb[2][8];       // corner vectors, buffer = unit&1 (== nt)
    float  cw[2][4];       // folded bilinear weights
    bool   inwf[2];        // in-window flag
    int    gidx[2][4];     // global fallback row indices
    half8  afb[2][8];      // A-fragments, buffer = tap&1

#define LDSRD(r, kc) (*(const uint4v*)&win[(r) * CC + ((((hi) + ((kc) << 2)) ^ ((r) & 7)) << 3)])

    // ISSUE(u): coords + 8 ds_reads for unit u; on nt==0 also prefetch
    // offsets for tap k+2 (ring) and A-frags for tap k.
#define ISSUE(u) do {                                                           \
        if ((((u) & 1) == 0) && (((u) >> 1) + 2 < KK)) {                        \
            _Pragma("unroll")                                                   \
            for (int nt = 0; nt < 2; ++nt) {                                    \
                ox[(((u) >> 1) + 2) % 3][nt] =                                  \
                    offpx[(size_t)(2 * (((u) >> 1) + 2) + 0) * HWSZ + nt * WWI];\
                oy[(((u) >> 1) + 2) % 3][nt] =                                  \
                    offpx[(size_t)(2 * (((u) >> 1) + 2) + 1) * HWSZ + nt * WWI];\
            }                                                                   \
        }                                                                       \
        if (((u) & 1) == 0) {                                                   \
            const unsigned short* wk = waf + (size_t)((u) >> 1) * 8 * 512 + lane * 8; \
            _Pragma("unroll")                                                   \
            for (int q = 0; q < 8; ++q)                                         \
                afb[((u) >> 1) & 1][q] = *(const half8*)(wk + (size_t)q * 512); \
        }                                                                       \
        const float gx = ox[((u) >> 1) % 3][(u) & 1] + (float)(x0 + fm);        \
        const float gy = oy[((u) >> 1) % 3][(u) & 1] + (float)(y0 + wave * 2 + ((u) & 1)); \
        const float fxf = floorf(gx), fyf = floorf(gy);                         \
        const float fx = gx - fxf, fy = gy - fyf;                               \
        const int ux0 = (int)fxf - 1, ux1 = (int)fxf;                           \
        const int uy0 = (int)fyf - 1, uy1 = (int)fyf;                           \
        const float vx0 = ((unsigned)ux0 < (unsigned)WWI) ? 1.0f : 0.0f;        \
        const float vx1 = ((unsigned)ux1 < (unsigned)WWI) ? 1.0f : 0.0f;        \
        const float vy0 = ((unsigned)uy0 < (unsigned)HH) ? 1.0f : 0.0f;         \
        const float vy1 = ((unsigned)uy1 < (unsigned)HH) ? 1.0f : 0.0f;         \
        cw[(u) & 1][0] = (1.0f - fy) * (1.0f - fx) * vy0 * vx0;                 \
        cw[(u) & 1][1] = (1.0f - fy) * fx          * vy0 * vx1;                 \
        cw[(u) & 1][2] = fy          * (1.0f - fx) * vy1 * vx0;                 \
        cw[(u) & 1][3] = fy          * fx          * vy1 * vx1;                 \
        const int cx0 = iclamp(ux0, 0, WWI - 1), cx1 = iclamp(ux1, 0, WWI - 1); \
        const int cy0 = iclamp(uy0, 0, HH - 1),  cy1 = iclamp(uy1, 0, HH - 1);  \
        inwf[(u) & 1] = (cx0 >= xleft) & (cx1 <= xleft + WNX - 1)               \
                      & (cy0 >= ytop) & (cy1 <= ytop + WNY - 1);                \
        gidx[(u) & 1][0] = cy0 * WWI + cx0;  gidx[(u) & 1][1] = cy0 * WWI + cx1;\
        gidx[(u) & 1][2] = cy1 * WWI + cx0;  gidx[(u) & 1][3] = cy1 * WWI + cx1;\
        const int wx0 = iclamp(cx0 - xleft, 0, WNX - 1);                        \
        const int wx1 = iclamp(cx1 - xleft, 0, WNX - 1);                        \
        const int wy0 = iclamp(cy0 - ytop, 0, WNY - 1);                         \
        const int wy1 = iclamp(cy1 - ytop, 0, WNY - 1);                         \
        const int r00 = wy0 * WNX + wx0, r01 = wy0 * WNX + wx1;                 \
        const int r10 = wy1 * WNX + wx0, r11 = wy1 * WNX + wx1;                 \
        cb[(u) & 1][0] = LDSRD(r00, 0);  cb[(u) & 1][1] = LDSRD(r00, 1);        \
        cb[(u) & 1][2] = LDSRD(r01, 0);  cb[(u) & 1][3] = LDSRD(r01, 1);        \
        cb[(u) & 1][4] = LDSRD(r10, 0);  cb[(u) & 1][5] = LDSRD(r10, 1);        \
        cb[(u) & 1][6] = LDSRD(r11, 0);  cb[(u) & 1][7] = LDSRD(r11, 1);        \
    } while (0)

    // PROC(u): pin corner regs (loads complete HERE), rare global fallback,
    // packed-fp16 interp, 8 MFMA into acc[nt].
#define PROC(u) do {                                                            \
        asm volatile("" : "+v"(cb[(u) & 1][0]), "+v"(cb[(u) & 1][1]),           \
                          "+v"(cb[(u) & 1][2]), "+v"(cb[(u) & 1][3]),           \
                          "+v"(cb[(u) & 1][4]), "+v"(cb[(u) & 1][5]),           \
                          "+v"(cb[(u) & 1][6]), "+v"(cb[(u) & 1][7]));          \
        uint4v A0 = cb[(u) & 1][0], A1 = cb[(u) & 1][1];                        \
        uint4v B0 = cb[(u) & 1][2], B1 = cb[(u) & 1][3];                        \
        uint4v C0 = cb[(u) & 1][4], C1 = cb[(u) & 1][5];                        \
        uint4v D0 = cb[(u) & 1][6], D1 = cb[(u) & 1][7];                        \
        if (!inwf[(u) & 1]) {                                                   \
            const unsigned short* g00 = xtb + (size_t)gidx[(u) & 1][0] * CC;    \
            const unsigned short* g01 = xtb + (size_t)gidx[(u) & 1][1] * CC;    \
            const unsigned short* g10 = xtb + (size_t)gidx[(u) & 1][2] * CC;    \
            const unsigned short* g11 = xtb + (size_t)gidx[(u) & 1][3] * CC;    \
            A0 = *(const uint4v*)(g00 + c0s);  A1 = *(const uint4v*)(g00 + c1s);\
            B0 = *(const uint4v*)(g01 + c0s);  B1 = *(const uint4v*)(g01 + c1s);\
            C0 = *(const uint4v*)(g10 + c0s);  C1 = *(const uint4v*)(g10 + c1s);\
            D0 = *(const uint4v*)(g11 + c0s);  D1 = *(const uint4v*)(g11 + c1s);\
        }                                                                       \
        const _Float16 hw00 = (_Float16)cw[(u) & 1][0];                         \
        const _Float16 hw01 = (_Float16)cw[(u) & 1][1];                         \
        const _Float16 hw10 = (_Float16)cw[(u) & 1][2];                         \
        const _Float16 hw11 = (_Float16)cw[(u) & 1][3];                         \
        const h2 w00v = {hw00, hw00}, w01v = {hw01, hw01};                      \
        const h2 w10v = {hw10, hw10}, w11v = {hw11, hw11};                      \
        half8 bf0, bf1;                                                         \
        h2* rp0 = (h2*)&bf0;                                                    \
        h2* rp1 = (h2*)&bf1;                                                    \
        _Pragma("unroll")                                                       \
        for (int i = 0; i < 4; ++i) {                                           \
            h2 r0 = u2h(A0[i]) * w00v;                                          \
            r0 += u2h(B0[i]) * w01v;                                            \
            r0 += u2h(C0[i]) * w10v;                                            \
            r0 += u2h(D0[i]) * w11v;                                            \
            rp0[i] = r0;                                                        \
            h2 r1 = u2h(A1[i]) * w00v;                                          \
            r1 += u2h(B1[i]) * w01v;                                            \
            r1 += u2h(C1[i]) * w10v;                                            \
            r1 += u2h(D1[i]) * w11v;                                            \
            rp1[i] = r1;                                                        \
        }                                                                       \
        _Pragma("unroll")                                                       \
        for (int m = 0; m < 4; ++m)                                             \
            acc[(u) & 1][m] = __builtin_amdgcn_mfma_f32_16x16x32_f16(           \
                afb[((u) >> 1) & 1][m], bf0, acc[(u) & 1][m], 0, 0, 0);         \
        _Pragma("unroll")                                                       \
        for (int m = 0; m < 4; ++m)                                             \
            acc[(u) & 1][m] = __builtin_amdgcn_mfma_f32_16x16x32_f16(           \
                afb[((u) >> 1) & 1][4 + m], bf1, acc[(u) & 1][m], 0, 0, 0);     \
    } while (0)

    // depth-2 pipeline over 18 (tap,nt) units
    ISSUE(0);  ISSUE(1);
    PROC(0);   ISSUE(2);
    PROC(1);   ISSUE(3);
    PROC(2);   ISSUE(4);
    PROC(3);   ISSUE(5);
    PROC(4);   ISSUE(6);
    PROC(5);   ISSUE(7);
    PROC(6);   ISSUE(8);
    PROC(7);   ISSUE(9);
    PROC(8);   ISSUE(10);
    PROC(9);   ISSUE(11);
    PROC(10);  ISSUE(12);
    PROC(11);  ISSUE(13);
    PROC(12);  ISSUE(14);
    PROC(13);  ISSUE(15);
    PROC(14);  ISSUE(16);
    PROC(15);  ISSUE(17);
    PROC(16);
    PROC(17);

#undef ISSUE
#undef PROC
#undef LDSRD

    // epilogue: D col = fm (px), D row = hi*4 + j within m-tile -> o = m*16+hi*4+j
#pragma unroll
    for (int nt = 0; nt < 2; ++nt) {
        float* outb = out + (size_t)b * OO * HWSZ
                          + (size_t)(y0 + wave * 2 + nt) * WWI + x0 + fm;
#pragma unroll
        for (int m = 0; m < 4; ++m) {
            const int ob = m * 16 + hi * 4;
            const float4 bs = *(const float4*)(bias + ob);
#pragma unroll
            for (int j = 0; j < 4; ++j) {
                outb[(size_t)(ob + j) * HWSZ] = acc[nt][m][j] + ((const float*)&bs)[j];
            }
        }
    }
}

// ---------- fallback (round-1 fp32 path, used only if ws too small) ----------
__global__ __launch_bounds__(256) void deform_conv_fallback(
        const float* __restrict__ x, const float* __restrict__ off,
        const float* __restrict__ wmat, const float* __restrict__ bias,
        float* __restrict__ out) {
    const int b = blockIdx.y;
    const int p = blockIdx.x * 256 + threadIdx.x;
    const int wo = p & (WWI - 1);
    const int ho = p >> 7;
    const float* xb = x + (size_t)b * CC * HWSZ;
    const float* offb = off + (size_t)b * 2 * KK * HWSZ + p;
    float acc[OO];
#pragma unroll
    for (int o = 0; o < OO; ++o) acc[o] = 0.0f;
#pragma unroll 1
    for (int k = 0; k < KK; ++k) {
        const float gx = offb[(size_t)(2 * k + 0) * HWSZ] + (float)wo;
        const float gy = offb[(size_t)(2 * k + 1) * HWSZ] + (float)ho;
        const float fxf = floorf(gx), fyf = floorf(gy);
        const float fx = gx - fxf, fy = gy - fyf;
        const int ux0 = (int)fxf - 1, ux1 = (int)fxf;
        const int uy0 = (int)fyf - 1, uy1 = (int)fyf;
        const float vx0 = ((unsigned)ux0 < (unsigned)WWI) ? 1.0f : 0.0f;
        const float vx1 = ((unsigned)ux1 < (unsigned)WWI) ? 1.0f : 0.0f;
        const float vy0 = ((unsigned)uy0 < (unsigned)HH) ? 1.0f : 0.0f;
        const float vy1 = ((unsigned)uy1 < (unsigned)HH) ? 1.0f : 0.0f;
        const float w00 = (1.0f - fy) * (1.0f - fx) * vy0 * vx0;
        const float w01 = (1.0f - fy) * fx * vy0 * vx1;
        const float w10 = fy * (1.0f - fx) * vy1 * vx0;
        const float w11 = fy * fx * vy1 * vx1;
        const int cx0 = iclamp(ux0, 0, WWI - 1), cx1 = iclamp(ux1, 0, WWI - 1);
        const int cy0 = iclamp(uy0, 0, HH - 1), cy1 = iclamp(uy1, 0, HH - 1);
        const int i00 = cy0 * WWI + cx0, i01 = cy0 * WWI + cx1;
        const int i10 = cy1 * WWI + cx0, i11 = cy1 * WWI + cx1;
#pragma unroll 4
        for (int c = 0; c < CC; ++c) {
            const float* xc = xb + (size_t)c * HWSZ;
            const float v = w00 * xc[i00] + w01 * xc[i01] + w10 * xc[i10] + w11 * xc[i11];
            const float* wrow = wmat + (size_t)(k * CC + c);
#pragma unroll
            for (int o = 0; o < OO; ++o) acc[o] = fmaf(wrow[(size_t)o * II], v, acc[o]);
        }
    }
    float* outb = out + (size_t)b * OO * HWSZ + p;
#pragma unroll
    for (int o = 0; o < OO; ++o) outb[(size_t)o * HWSZ] = acc[o] + bias[o];
}

extern "C" void kernel_launch(void* const* d_in, const int* in_sizes, int n_in,
                              void* d_out, int out_size, void* d_ws, size_t ws_size,
                              hipStream_t stream) {
    const float* x    = (const float*)d_in[0];
    const float* off  = (const float*)d_in[1];
    const float* w    = (const float*)d_in[2];
    const float* bias = (const float*)d_in[3];
    float* out = (float*)d_out;

    const size_t xt_bytes  = (size_t)BB * HWSZ * CC * sizeof(unsigned short); // 16.78 MB
    const size_t waf_bytes = (size_t)72 * 512 * sizeof(unsigned short);       // 73728 B

    if (ws_size >= xt_bytes + waf_bytes) {
        unsigned short* xt  = (unsigned short*)d_ws;
        unsigned short* wfp = (unsigned short*)((char*)d_ws + xt_bytes);
        prep_xt<<<dim3((HWSZ / 64) * BB), 256, 0, stream>>>(x, xt);
        prep_waf<<<(72 * 512 + 255) / 256, 256, 0, stream>>>(w, wfp);
        // 8 images x (8 y-patches * 8 x-patches) = 512 blocks, 72KB dyn LDS
        deform_mfma9<<<dim3(BB * (HH / PYH) * (WWI / PXW)), dim3(512),
                       WROWS * CC * sizeof(unsigned short), stream>>>(
            xt, off, wfp, bias, out);
    } else {
        deform_conv_fallback<<<dim3(HWSZ / 256, BB), 256, 0, stream>>>(x, off, w, bias, out);
    }
}